// Round 6
// baseline (188.074 us; speedup 1.0000x reference)
//
#include <hip/hip_runtime.h>

#define N_NODES 100000
#define N_EDGES 1600000
#define EMBED_DIM 64

#define RPB 256                                   // rows per bucket
#define NBKT ((N_NODES + RPB - 1) / RPB)          // 391
#define CAP 4608                                  // slots per bucket (mean 4092, +8 sigma)
#define TILE 2048                                 // edges per binA block (31KB LDS -> 5 blk/CU)
#define NTILE ((N_EDGES + TILE - 1) / TILE)       // 782
#define OVCAP 8192                                // overflow backstop

// ---------- pass A: tile counting-sort into bucket regions (dense writes) ----------
__global__ __launch_bounds__(256) void k_binA(const int* __restrict__ rows,
                                              const int* __restrict__ cols,
                                              const float* __restrict__ vals,
                                              int* __restrict__ gcur,
                                              int2* __restrict__ packed,
                                              int* __restrict__ ov_cnt,
                                              int4* __restrict__ ov) {
    __shared__ int hist[NBKT];
    __shared__ int off[NBKT];
    __shared__ int cur[NBKT];
    __shared__ int gbase[NBKT];
    __shared__ int ssum[256];
    __shared__ int2 stage[TILE];   // 16 KB
    __shared__ int dg[TILE];       // 8 KB
    const int tid = threadIdx.x;
    const int e0 = blockIdx.x * TILE;

    for (int i = tid; i < NBKT; i += 256) hist[i] = 0;
    __syncthreads();

    for (int i = tid; i < TILE; i += 256) {
        int e = e0 + i;
        if (e < N_EDGES) atomicAdd(&hist[rows[e] >> 8], 1);
    }
    __syncthreads();

    // exclusive scan over NBKT (2 items/thread)
    int b0 = 2 * tid, b1 = 2 * tid + 1;
    int h0 = (b0 < NBKT) ? hist[b0] : 0;
    int h1 = (b1 < NBKT) ? hist[b1] : 0;
    ssum[tid] = h0 + h1;
    __syncthreads();
    for (int o = 1; o < 256; o <<= 1) {
        int a = ssum[tid];
        int add = (tid >= o) ? ssum[tid - o] : 0;
        __syncthreads();
        ssum[tid] = a + add;
        __syncthreads();
    }
    int base = (tid == 0) ? 0 : ssum[tid - 1];
    if (b0 < NBKT) { off[b0] = base; cur[b0] = base; }
    if (b1 < NBKT) { off[b1] = base + h0; cur[b1] = base + h0; }

    for (int b = tid; b < NBKT; b += 256) {
        int c = hist[b];
        gbase[b] = c ? atomicAdd(&gcur[b], c) : 0;
    }
    __syncthreads();

    for (int i = tid; i < TILE; i += 256) {
        int e = e0 + i;
        if (e < N_EDGES) {
            int r = rows[e];
            int b = r >> 8;
            int p = atomicAdd(&cur[b], 1);
            stage[p] = make_int2(((r & (RPB - 1)) << 17) | cols[e],
                                 __float_as_int(vals[e]));
            int d = gbase[b] + (p - off[b]);
            dg[p] = (d < CAP) ? (b * CAP + d) : (0x40000000 | b);
        }
    }
    __syncthreads();

    int total = ssum[255];
    for (int j = tid; j < total; j += 256) {
        int d = dg[j];
        int2 ev = stage[j];
        if (d & 0x40000000) {
            int b = d & 0xFFFF;
            int ovi = atomicAdd(ov_cnt, 1);
            if (ovi < OVCAP) {
                int r = b * RPB + (((unsigned)ev.x) >> 17);
                ov[ovi] = make_int4(r, ev.x & 0x1FFFF, ev.y, 0);
            }
        } else {
            packed[d] = ev;
        }
    }
}

// ---------- pass B (ping-pong): per-bucket row-sort, strip lrow, emit CSR ----------
__global__ __launch_bounds__(256) void k_binB_pp(const int* __restrict__ gcur,
                                                 const int2* __restrict__ packed,
                                                 int2* __restrict__ sorted,
                                                 int* __restrict__ row_ptr,
                                                 int* __restrict__ cnt) {
    __shared__ int h[RPB];
    __shared__ int s[RPB];
    __shared__ int cur[RPB];
    const int b = blockIdx.x;
    const int tid = threadIdx.x;
    int n = gcur[b];
    if (n > CAP) n = CAP;
    const int base = b * CAP;

    h[tid] = 0;
    __syncthreads();
    for (int j = tid; j < n; j += 256)
        atomicAdd(&h[((unsigned)packed[base + j].x) >> 17], 1);
    __syncthreads();

    int hv = h[tid];
    s[tid] = hv;
    __syncthreads();
    for (int o = 1; o < 256; o <<= 1) {
        int a = s[tid];
        int add = (tid >= o) ? s[tid - o] : 0;
        __syncthreads();
        s[tid] = a + add;
        __syncthreads();
    }
    int ofs = (tid == 0) ? 0 : s[tid - 1];
    cur[tid] = ofs;
    int r = b * RPB + tid;
    if (r < N_NODES) {
        row_ptr[r] = base + ofs;
        cnt[r] = hv;
    }
    __syncthreads();

    for (int j = tid; j < n; j += 256) {
        int2 e = packed[base + j];   // L2-hot second read
        int lr = ((unsigned)e.x) >> 17;
        int p = atomicAdd(&cur[lr], 1);
        sorted[base + p] = make_int2(e.x & 0x1FFFF, e.y);
    }
}

// ---------- pass B (in-place fallback): LDS stage ----------
__global__ __launch_bounds__(256) void k_binB_ip(const int* __restrict__ gcur,
                                                 int2* __restrict__ packed,
                                                 int* __restrict__ row_ptr,
                                                 int* __restrict__ cnt) {
    __shared__ int2 stage[CAP];    // 36 KB
    __shared__ int h[RPB];
    __shared__ int s[RPB];
    __shared__ int cur[RPB];
    const int b = blockIdx.x;
    const int tid = threadIdx.x;
    int n = gcur[b];
    if (n > CAP) n = CAP;
    const int base = b * CAP;

    h[tid] = 0;
    __syncthreads();
    for (int j = tid; j < n; j += 256) {
        int2 e = packed[base + j];
        stage[j] = e;
        atomicAdd(&h[((unsigned)e.x) >> 17], 1);
    }
    __syncthreads();

    int hv = h[tid];
    s[tid] = hv;
    __syncthreads();
    for (int o = 1; o < 256; o <<= 1) {
        int a = s[tid];
        int add = (tid >= o) ? s[tid - o] : 0;
        __syncthreads();
        s[tid] = a + add;
        __syncthreads();
    }
    int ofs = (tid == 0) ? 0 : s[tid - 1];
    cur[tid] = ofs;
    int r = b * RPB + tid;
    if (r < N_NODES) {
        row_ptr[r] = base + ofs;
        cnt[r] = hv;
    }
    __syncthreads();

    for (int j = tid; j < n; j += 256) {
        int2 e = stage[j];
        int lr = ((unsigned)e.x) >> 17;
        int p = atomicAdd(&cur[lr], 1);
        packed[base + p] = make_int2(e.x & 0x1FFFF, e.y);
    }
}

// ---------- gather: one wave per row; SCALAR edge-list loads + v_fmac ----------
// beg/deg are readfirstlane'd -> edge addresses are wave-uniform -> compiler
// emits s_load (SMEM pipe) for the (col,val) pairs; col*256 byte base computed
// on SALU; the VALU does only one v_fmac per edge. 8 X-loads in flight/chunk.
__global__ __launch_bounds__(256) void k_gather(const float* __restrict__ x,
                                                const int* __restrict__ row_ptr,
                                                const int* __restrict__ cnt,
                                                const int2* __restrict__ ep,
                                                float* __restrict__ out) {
    int wid = (blockIdx.x * 256 + threadIdx.x) >> 6;
    int lane = threadIdx.x & 63;
    if (wid >= N_NODES) return;
    int beg = __builtin_amdgcn_readfirstlane(row_ptr[wid]);
    int deg = __builtin_amdgcn_readfirstlane(cnt[wid]);
    const int2* p = ep + beg;
    float acc = 0.f;
    int k = 0;
    for (; k + 8 <= deg; k += 8) {
        int2 e[8];
#pragma unroll
        for (int i = 0; i < 8; ++i) e[i] = p[k + i];   // s_load_dwordx16 x2
#pragma unroll
        for (int i = 0; i < 8; ++i)
            acc += __int_as_float(e[i].y) * x[(e[i].x << 6) + lane];
    }
    for (; k < deg; ++k) {
        int2 e = p[k];
        acc += __int_as_float(e.y) * x[(e.x << 6) + lane];
    }
    out[wid * EMBED_DIM + lane] = acc;
}

// ---------- overflow cleanup (expected n==0) ----------
__global__ __launch_bounds__(256) void k_overflow(const float* __restrict__ x,
                                                  const int* __restrict__ ov_cnt,
                                                  const int4* __restrict__ ov,
                                                  float* __restrict__ out) {
    int n = *ov_cnt;
    if (n > OVCAP) n = OVCAP;
    int lane = threadIdx.x & 63;
    for (int idx = (blockIdx.x * 256 + threadIdx.x) >> 6; idx < n;
         idx += gridDim.x * 4) {
        int4 e = ov[idx];
        atomicAdd(&out[e.x * EMBED_DIM + lane],
                  __int_as_float(e.z) * x[e.y * EMBED_DIM + lane]);
    }
}

// ---------- fallback (ws too small): atomic scatter ----------
__global__ __launch_bounds__(256) void spmm_scatter_kernel(
    const float* __restrict__ x, const float* __restrict__ vals,
    const int* __restrict__ rows, const int* __restrict__ cols,
    float* __restrict__ out) {
    const int wave_in_block = threadIdx.x >> 6;
    const int lane = threadIdx.x & 63;
    const int e = blockIdx.x * 4 + wave_in_block;
    if (e >= N_EDGES) return;
    const float m = vals[e] * x[cols[e] * EMBED_DIM + lane];
    atomicAdd(&out[rows[e] * EMBED_DIM + lane], m);
}

extern "C" void kernel_launch(void* const* d_in, const int* in_sizes, int n_in,
                              void* d_out, int out_size, void* d_ws, size_t ws_size,
                              hipStream_t stream) {
    const float* x    = (const float*)d_in[0];
    const float* vals = (const float*)d_in[1];
    const int*   rows = (const int*)d_in[2];
    const int*   cols = (const int*)d_in[3];
    float* out = (float*)d_out;

    // ws: packed[NBKT*CAP] int2 | (sorted[NBKT*CAP] int2)? | ov[OVCAP] int4 |
    //     gcur[NBKT] | ov_cnt | row_ptr[N] | cnt[N]
    const size_t packed_b = (size_t)NBKT * CAP * 8;   // 14,413,824
    const size_t ov_b     = (size_t)OVCAP * 16;
    const size_t tail_b   = ((size_t)NBKT + 1 + 2 * (size_t)N_NODES) * 4;
    const size_t need_pp  = 2 * packed_b + ov_b + tail_b;
    const size_t need_ip  = packed_b + ov_b + tail_b;

    if (ws_size < need_ip) {
        hipMemsetAsync(out, 0, (size_t)out_size * sizeof(float), stream);
        spmm_scatter_kernel<<<(N_EDGES + 3) / 4, 256, 0, stream>>>(x, vals, rows, cols, out);
        return;
    }

    const bool pp = (ws_size >= need_pp);
    int2* packed = (int2*)d_ws;
    int2* sorted = pp ? (int2*)((char*)d_ws + packed_b) : packed;
    char* rest   = (char*)d_ws + (pp ? 2 * packed_b : packed_b);
    int4* ov     = (int4*)rest;
    int*  gcur   = (int*)(rest + ov_b);
    int*  ov_cnt = gcur + NBKT;
    int*  row_ptr = ov_cnt + 1;
    int*  cnt     = row_ptr + N_NODES;

    hipMemsetAsync(gcur, 0, ((size_t)NBKT + 1) * sizeof(int), stream);  // gcur + ov_cnt

    k_binA<<<NTILE, 256, 0, stream>>>(rows, cols, vals, gcur, packed, ov_cnt, ov);
    if (pp)
        k_binB_pp<<<NBKT, 256, 0, stream>>>(gcur, packed, sorted, row_ptr, cnt);
    else
        k_binB_ip<<<NBKT, 256, 0, stream>>>(gcur, packed, row_ptr, cnt);
    k_gather<<<(N_NODES * 64 + 255) / 256, 256, 0, stream>>>(x, row_ptr, cnt, sorted, out);
    k_overflow<<<64, 256, 0, stream>>>(x, ov_cnt, ov, out);
}